// Round 12
// baseline (2620.698 us; speedup 1.0000x reference)
//
#include <hip/hip_runtime.h>

#define B_ 128
#define T_ 270
#define XR 4104   // 8 + 64*64
#define H_ 256
#define HSTR 264                    // shorts per hls row (528 B)

#define LDSB_BYTES 151552           // 4 waves * 37 frags * 1 KB
#define HLS_OFF    151552
#define HEADP_OFF  160000
#define SMEM_TOTAL 160256           // <= 163840

// spack: full region 512 frags * 1 KB = 512 KB; compact kf8 region 64 * 512 B
#define SPACK_FULL_SHORTS  262144
#define SPACK_SHORTS       (262144 + 16384)

typedef __attribute__((ext_vector_type(8))) short short8v;
typedef __attribute__((ext_vector_type(4))) float f32x4;

__device__ inline unsigned short f2bf(float f) {
  unsigned u = __builtin_bit_cast(unsigned, f);
  u += 0x7fffu + ((u >> 16) & 1u);
  return (unsigned short)(u >> 16);
}
__device__ inline float sigm(float x) { return 1.0f / (1.0f + __expf(-x)); }
__device__ inline float tanh_f(float x) {
  float t = __expf(-2.0f * fabsf(x));
  float r = (1.0f - t) / (1.0f + t);
  return copysignf(r, x);
}
__device__ inline short8v pack8(const float* p) {
  float4 a = *(const float4*)p, b = *(const float4*)(p + 4);
  short8v v;
  v[0] = (short)f2bf(a.x); v[1] = (short)f2bf(a.y);
  v[2] = (short)f2bf(a.z); v[3] = (short)f2bf(a.w);
  v[4] = (short)f2bf(b.x); v[5] = (short)f2bf(b.y);
  v[6] = (short)f2bf(b.z); v[7] = (short)f2bf(b.w);
  return v;
}
__device__ inline short8v pinned(short8v v) {       // arch-VGPR pin
  union { short8v s; float f[4]; } u;
  u.s = v;
  asm volatile("" : "+v"(u.f[0]), "+v"(u.f[1]), "+v"(u.f[2]), "+v"(u.f[3]));
  return u.s;
}
__device__ inline short8v pinned_a(short8v v) {     // AGPR pin
  union { short8v s; float f[4]; } u;
  u.s = v;
  asm volatile("" : "+a"(u.f[0]), "+a"(u.f[1]), "+a"(u.f[2]), "+a"(u.f[3]));
  return u.s;
}
#define MFMA(a, b, c) __builtin_amdgcn_mfma_f32_16x16x32_bf16((a), (b), (c), 0, 0, 0)

// ws layout
#define FEAT16_B ((size_t)T_ * B_ * 16 * 2)        // 1,105,920
#define SPACK_B  ((size_t)SPACK_SHORTS * 2)        //   557,056
#define WS_NEED  (FEAT16_B + SPACK_B)

// ---------------------------------------------------------------------------
// Kernel 1: per-(b,t) CNN tower. One block per image. Writes bf16 feat.
// ---------------------------------------------------------------------------
__global__ __launch_bounds__(256) void cnn_kernel(
    const float* __restrict__ x,
    const float* __restrict__ c1w_, const float* __restrict__ c1b_,
    const float* __restrict__ c2w_, const float* __restrict__ c2b_,
    const float* __restrict__ fcw, const float* __restrict__ fcb,
    unsigned short* __restrict__ feat16)
{
  __shared__ float img[64 * 68];
  __shared__ float p1[2 * 15 * 16];
  __shared__ float p2[36];
  __shared__ float wsm[96];
  const int tid = threadIdx.x;
  const int bt = blockIdx.x;
  const int b = bt & 127, t = bt >> 7;

  const float* src = x + ((long)b * T_ + t) * XR;

  if (tid < 18) wsm[tid] = c1w_[tid];
  else if (tid < 20) wsm[tid] = c1b_[tid - 18];
  else if (tid < 92) wsm[tid] = c2w_[tid - 20];
  else if (tid < 96) wsm[tid] = c2b_[tid - 92];

  {
    const float4* s4 = (const float4*)(src + 8);
#pragma unroll
    for (int i0 = 0; i0 < 4; i0++) {
      int i = tid + i0 * 256;
      float4 v = s4[i];
      int e = i * 4;
      *((float4*)&img[(e >> 6) * 68 + (e & 63)]) = v;
    }
  }
  __syncthreads();

  if (tid < 225) {
    int py = tid / 15, px = tid - (tid / 15) * 15;
    float w0[9], w1[9];
#pragma unroll
    for (int j = 0; j < 9; j++) { w0[j] = wsm[j]; w1[j] = wsm[9 + j]; }
    const float b0 = wsm[18], b1v = wsm[19];
    float m0 = -1e30f, m1 = -1e30f;
    for (int dy = 0; dy < 4; dy++) {
      for (int dx = 0; dx < 4; dx++) {
        const float* ip = &img[(py * 4 + dy) * 68 + px * 4 + dx];
        float s0 = b0, s1 = b1v;
#pragma unroll
        for (int ky = 0; ky < 3; ky++) {
#pragma unroll
          for (int kx = 0; kx < 3; kx++) {
            float v = ip[ky * 68 + kx];
            s0 = fmaf(v, w0[ky * 3 + kx], s0);
            s1 = fmaf(v, w1[ky * 3 + kx], s1);
          }
        }
        m0 = fmaxf(m0, s0); m1 = fmaxf(m1, s1);
      }
    }
    p1[py * 16 + px] = fmaxf(m0, 0.f);
    p1[240 + py * 16 + px] = fmaxf(m1, 0.f);
  }
  __syncthreads();

  if (tid < 36) {
    int ch = tid / 9, rem = tid - ch * 9;
    int py = rem / 3, px = rem - py * 3;
    float m = -1e30f;
    for (int dy = 0; dy < 4; dy++) {
      for (int dx = 0; dx < 4; dx++) {
        int y = py * 4 + dy, xx = px * 4 + dx;
        float s = wsm[92 + ch];
#pragma unroll
        for (int ic = 0; ic < 2; ic++)
#pragma unroll
          for (int ky = 0; ky < 3; ky++)
#pragma unroll
            for (int kx = 0; kx < 3; kx++)
              s = fmaf(p1[ic * 240 + (y + ky) * 16 + xx + kx],
                       wsm[20 + ((ch * 2 + ic) * 3 + ky) * 3 + kx], s);
        m = fmaxf(m, s);
      }
    }
    p2[tid] = fmaxf(m, 0.f);
  }
  __syncthreads();

  unsigned short* fr = feat16 + ((long)t * B_ + b) * 16;
  if (tid < 8) {
    float s = fcb[tid];
#pragma unroll
    for (int j = 0; j < 36; j++) s = fmaf(p2[j], fcw[tid * 36 + j], s);
    fr[8 + tid] = f2bf(s);
  } else if (tid < 16) {
    fr[tid - 8] = f2bf(src[tid - 8]);
  }
}

// ---------------------------------------------------------------------------
// Kernel 1b: pack weights bf16 in the lstm per-lane layout.
// Full region: F = (w*16+u)*8+kf (kf 0..7, whh), addr = F*512 + lane*8 shorts.
//   col(u,w,lane) = (u>>2)*256 + w*64 + (u&3)*16 + (lane&15); K = kf*32+(lane>>4)*8.
// Compact kf8 region (w_ih; real data only in lanes 0..31):
//   G = w*16+u, addr = 262144 + G*256 + lane32*8 shorts.
// ---------------------------------------------------------------------------
__global__ __launch_bounds__(256) void pack_kernel(
    const float* __restrict__ whh, const float* __restrict__ wih,
    unsigned short* __restrict__ spack)
{
  const int idx = blockIdx.x * 256 + threadIdx.x;
  if (idx < 32768) {
    const int lane = idx & 63, F = idx >> 6;
    const int kf = F & 7, u = (F >> 3) & 15, w = F >> 7;
    const int col = (u >> 2) * 256 + w * 64 + (u & 3) * 16 + (lane & 15);
    *(short8v*)(spack + (size_t)F * 512 + (size_t)lane * 8) =
        pack8(whh + col * 256 + kf * 32 + (lane >> 4) * 8);
  } else if (idx < 32768 + 2048) {
    const int i2 = idx - 32768;
    const int lane = i2 & 31, G = i2 >> 5;
    const int u = G & 15, w = G >> 4;
    const int col = (u >> 2) * 256 + w * 64 + (u & 3) * 16 + (lane & 15);
    *(short8v*)(spack + SPACK_FULL_SHORTS + (size_t)G * 256 + (size_t)lane * 8) =
        pack8(wih + col * 16 + (lane >> 4) * 8);
  }
}

// ---------------------------------------------------------------------------
// Kernel 2: LSTM, ZERO inter-block communication. 8 blocks x 16 batch rows,
// each block computes the FULL 256 hidden dims. 256 thr = 4 waves, 1/SIMD
// -> 512 regs/wave (256 arch + 256 AGPR). Wave w owns dims w*64..+63 for all
// 4 gates (16 col-frags); i,f,g,o of every cell live in one lane's acc.
// Weight tiers/wave (all indices compile-time, rule #20):
//   AGPR : kf0..2 (48 frags) + acc(64)        = 256 AGPR
//   arch : kf3 all + kf4 u0..7 (24 frags, 96)
//   LDS  : kf5,kf6 all + kf7 u0..4 (37 frags) = 148 KB
//   L2   : kf4 u8..15, kf7 u5..15, kf8(compact) ~27 KB/wave/step, batched
// Exchange deleted: r1/r3/r7/r8 all pinned at ~4.5-4.9 us/step on the
// agent-scope fabric chain (FETCH showed peer traffic bypassing L2).
// ---------------------------------------------------------------------------
__global__ __launch_bounds__(256, 1) void lstm_kernel(
    const unsigned short* __restrict__ feat16,
    const float* __restrict__ bih, const float* __restrict__ bhh,
    const float* __restrict__ h0, const float* __restrict__ c0,
    const float* __restrict__ hw, const float* __restrict__ hdb,
    const unsigned short* __restrict__ spack, float* __restrict__ out)
{
  extern __shared__ char smem[];
  unsigned short* ldsB = (unsigned short*)smem;
  unsigned short* hls  = (unsigned short*)(smem + HLS_OFF);
  float* headp = (float*)(smem + HEADP_OFF);     // [4][16]

  const int tid = threadIdx.x;
  const int w = tid >> 6, lane = tid & 63;
  const int col15 = lane & 15, ko8 = (lane >> 4) * 8, rb = (lane >> 4) * 4;
  const int R0 = blockIdx.x * 16;
  const int ar = col15;                          // A-frag row

  const unsigned short* sb = spack + (size_t)(w * 16) * 8 * 512 + (size_t)lane * 8;
#define SFRAG(u, kf) (*(const short8v*)(sb + ((u) * 8 + (kf)) * 512))
  const unsigned short* cb =
      spack + SPACK_FULL_SHORTS + (size_t)(w * 16) * 256 + (size_t)(lane & 31) * 8;
#define CFRAG(u) (*(const short8v*)(cb + (u) * 256))

  // ---- register tiers
  short8v bA0[16], bA1[16], bA2[16];   // AGPR
  short8v bV3[16], bV4[8];             // arch
#pragma unroll
  for (int u = 0; u < 16; u++) {
    bA0[u] = pinned_a(SFRAG(u, 0));
    bA1[u] = pinned_a(SFRAG(u, 1));
    bA2[u] = pinned_a(SFRAG(u, 2));
    bV3[u] = pinned(SFRAG(u, 3));
  }
#pragma unroll
  for (int u = 0; u < 8; u++) bV4[u] = pinned(SFRAG(u, 4));

  // ---- LDS tier: s<16: kf5,u=s ; s<32: kf6,u=s-16 ; s<37: kf7,u=s-32
#pragma unroll
  for (int s = 0; s < 37; s++) {
    const int u = (s < 16) ? s : (s < 32) ? (s - 16) : (s - 32);
    const int kf = (s < 16) ? 5 : (s < 32) ? 6 : 7;
    *(short8v*)&ldsB[((w * 37 + s) * 64 + lane) * 8] = SFRAG(u, kf);
  }
#define LB(s) (*(const short8v*)&ldsB[((w * 37 + (s)) * 64 + lane) * 8])

  // ---- per-lane constants
  float bsr[16], hwr[4];
#pragma unroll
  for (int u = 0; u < 16; u++) {
    const int col = (u >> 2) * 256 + w * 64 + (u & 3) * 16 + col15;
    bsr[u] = bih[col] + bhh[col];
  }
#pragma unroll
  for (int q = 0; q < 4; q++) hwr[q] = hw[w * 64 + q * 16 + col15];
  const float hdb0 = hdb[0];

  // ---- c-state in registers; h0 -> LDS
  float cs[4][4];
#pragma unroll
  for (int q = 0; q < 4; q++)
#pragma unroll
    for (int rr = 0; rr < 4; rr++) {
      const int row = rb + rr, d = w * 64 + q * 16 + col15;
      cs[q][rr] = c0[(R0 + row) * H_ + d];
      hls[row * HSTR + d] = f2bf(h0[(R0 + row) * H_ + d]);
    }
  __syncthreads();

#define HFRAG(kf) (*(const short8v*)&hls[ar * HSTR + (kf) * 32 + ko8])
  const short8v z8 = (short8v){0, 0, 0, 0, 0, 0, 0, 0};

  for (int t = 0; t < T_; t++) {
    // ---- head output for t-1 (headp written before last barrier)
    if (w == 0 && lane < 16 && t > 0) {
      float s = hdb0 + headp[lane] + headp[16 + lane] + headp[32 + lane] + headp[48 + lane];
      out[(long)(R0 + lane) * T_ + (t - 1)] = s;
    }

    // feat A-frag (K slots 0..15 real, rest zero)
    short8v af8 = z8;
    if (ko8 < 16)
      af8 = *(const short8v*)(feat16 + ((size_t)t * B_ + R0 + ar) * 16 + ko8);

    // stream G1: kf4 u8..15 (8 frags)
    short8v g10 = SFRAG(8, 4),  g11 = SFRAG(9, 4),  g12 = SFRAG(10, 4), g13 = SFRAG(11, 4);
    short8v g14 = SFRAG(12, 4), g15 = SFRAG(13, 4), g16 = SFRAG(14, 4), g17 = SFRAG(15, 4);

    f32x4 acc[16];
#pragma unroll
    for (int u = 0; u < 16; u++) acc[u] = (f32x4){0.f, 0.f, 0.f, 0.f};

    // ---- AGPR tier: kf0..2
    {
      short8v a = HFRAG(0);
#pragma unroll
      for (int u = 0; u < 16; u++) acc[u] = MFMA(a, bA0[u], acc[u]);
    }
    {
      short8v a = HFRAG(1);
#pragma unroll
      for (int u = 0; u < 16; u++) acc[u] = MFMA(a, bA1[u], acc[u]);
    }
    {
      short8v a = HFRAG(2);
#pragma unroll
      for (int u = 0; u < 16; u++) acc[u] = MFMA(a, bA2[u], acc[u]);
    }
    // ---- arch tier: kf3 + kf4 u0..7, then consume G1
    {
      short8v a = HFRAG(3);
#pragma unroll
      for (int u = 0; u < 16; u++) acc[u] = MFMA(a, bV3[u], acc[u]);
    }
    {
      short8v a4 = HFRAG(4);
#pragma unroll
      for (int u = 0; u < 8; u++) acc[u] = MFMA(a4, bV4[u], acc[u]);
      acc[8]  = MFMA(a4, g10, acc[8]);   acc[9]  = MFMA(a4, g11, acc[9]);
      acc[10] = MFMA(a4, g12, acc[10]);  acc[11] = MFMA(a4, g13, acc[11]);
      acc[12] = MFMA(a4, g14, acc[12]);  acc[13] = MFMA(a4, g15, acc[13]);
      acc[14] = MFMA(a4, g16, acc[14]);  acc[15] = MFMA(a4, g17, acc[15]);
    }

    // stream G2: kf7 u5..15 (11 frags)
    short8v g20 = SFRAG(5, 7),  g21 = SFRAG(6, 7),  g22 = SFRAG(7, 7),  g23 = SFRAG(8, 7);
    short8v g24 = SFRAG(9, 7),  g25 = SFRAG(10, 7), g26 = SFRAG(11, 7), g27 = SFRAG(12, 7);
    short8v g28 = SFRAG(13, 7), g29 = SFRAG(14, 7), g2a = SFRAG(15, 7);

    // ---- LDS tier: kf5, kf6
    {
      short8v a = HFRAG(5);
#pragma unroll
      for (int u = 0; u < 16; u++) acc[u] = MFMA(a, LB(u), acc[u]);
    }
    // stream G3a: kf8 u0..7 (compact: lanes<32 carry data)
    short8v c80 = (lane < 32) ? CFRAG(0) : z8, c81 = (lane < 32) ? CFRAG(1) : z8;
    short8v c82 = (lane < 32) ? CFRAG(2) : z8, c83 = (lane < 32) ? CFRAG(3) : z8;
    short8v c84 = (lane < 32) ? CFRAG(4) : z8, c85 = (lane < 32) ? CFRAG(5) : z8;
    short8v c86 = (lane < 32) ? CFRAG(6) : z8, c87 = (lane < 32) ? CFRAG(7) : z8;
    {
      short8v a = HFRAG(6);
#pragma unroll
      for (int u = 0; u < 16; u++) acc[u] = MFMA(a, LB(16 + u), acc[u]);
    }
    // ---- kf7: LDS u0..4 + stream u5..15
    {
      short8v a7 = HFRAG(7);
#pragma unroll
      for (int u = 0; u < 5; u++) acc[u] = MFMA(a7, LB(32 + u), acc[u]);
      acc[5]  = MFMA(a7, g20, acc[5]);   acc[6]  = MFMA(a7, g21, acc[6]);
      acc[7]  = MFMA(a7, g22, acc[7]);   acc[8]  = MFMA(a7, g23, acc[8]);
      acc[9]  = MFMA(a7, g24, acc[9]);   acc[10] = MFMA(a7, g25, acc[10]);
      acc[11] = MFMA(a7, g26, acc[11]);  acc[12] = MFMA(a7, g27, acc[12]);
      acc[13] = MFMA(a7, g28, acc[13]);  acc[14] = MFMA(a7, g29, acc[14]);
      acc[15] = MFMA(a7, g2a, acc[15]);
    }
    // stream G3b: kf8 u8..15
    short8v c88 = (lane < 32) ? CFRAG(8) : z8,  c89 = (lane < 32) ? CFRAG(9) : z8;
    short8v c8a = (lane < 32) ? CFRAG(10) : z8, c8b = (lane < 32) ? CFRAG(11) : z8;
    short8v c8c = (lane < 32) ? CFRAG(12) : z8, c8d = (lane < 32) ? CFRAG(13) : z8;
    short8v c8e = (lane < 32) ? CFRAG(14) : z8, c8f = (lane < 32) ? CFRAG(15) : z8;
    // ---- kf8 (feat x w_ih)
    acc[0]  = MFMA(af8, c80, acc[0]);   acc[1]  = MFMA(af8, c81, acc[1]);
    acc[2]  = MFMA(af8, c82, acc[2]);   acc[3]  = MFMA(af8, c83, acc[3]);
    acc[4]  = MFMA(af8, c84, acc[4]);   acc[5]  = MFMA(af8, c85, acc[5]);
    acc[6]  = MFMA(af8, c86, acc[6]);   acc[7]  = MFMA(af8, c87, acc[7]);
    acc[8]  = MFMA(af8, c88, acc[8]);   acc[9]  = MFMA(af8, c89, acc[9]);
    acc[10] = MFMA(af8, c8a, acc[10]);  acc[11] = MFMA(af8, c8b, acc[11]);
    acc[12] = MFMA(af8, c8c, acc[12]);  acc[13] = MFMA(af8, c8d, acc[13]);
    acc[14] = MFMA(af8, c8e, acc[14]);  acc[15] = MFMA(af8, c8f, acc[15]);

    __syncthreads();   // all h(t) reads + headp(t-1) reads complete

    // ---- in-register LSTM cell: 16 cells/lane + h publish + head partial
    float ps[4] = {0.f, 0.f, 0.f, 0.f};
#pragma unroll
    for (int q = 0; q < 4; q++)
#pragma unroll
      for (int rr = 0; rr < 4; rr++) {
        float i_ = acc[q][rr]      + bsr[q];
        float f_ = acc[4 + q][rr]  + bsr[4 + q];
        float g_ = acc[8 + q][rr]  + bsr[8 + q];
        float o_ = acc[12 + q][rr] + bsr[12 + q];
        float cn = sigm(f_) * cs[q][rr] + sigm(i_) * tanh_f(g_);
        cs[q][rr] = cn;
        float hn = sigm(o_) * tanh_f(cn);
        hls[(rb + rr) * HSTR + w * 64 + q * 16 + col15] = f2bf(hn);
        ps[rr] += hn * hwr[q];
      }
#pragma unroll
    for (int off = 1; off <= 8; off <<= 1)
#pragma unroll
      for (int rr = 0; rr < 4; rr++) ps[rr] += __shfl_xor(ps[rr], off);
    if (col15 == 0)
#pragma unroll
      for (int rr = 0; rr < 4; rr++) headp[w * 16 + rb + rr] = ps[rr];

    __syncthreads();   // h(t+1) + headp(t) visible block-wide
  }

  // ---- final head output (t = T-1)
  if (w == 0 && lane < 16) {
    float s = hdb0 + headp[lane] + headp[16 + lane] + headp[32 + lane] + headp[48 + lane];
    out[(long)(R0 + lane) * T_ + (T_ - 1)] = s;
  }
}

// ---------------------------------------------------------------------------
extern "C" void kernel_launch(void* const* d_in, const int* in_sizes, int n_in,
                              void* d_out, int out_size, void* d_ws, size_t ws_size,
                              hipStream_t stream) {
  const float* x   = (const float*)d_in[0];
  const float* c1w = (const float*)d_in[1];
  const float* c1b = (const float*)d_in[2];
  const float* c2w = (const float*)d_in[3];
  const float* c2b = (const float*)d_in[4];
  const float* fcw = (const float*)d_in[5];
  const float* fcb = (const float*)d_in[6];
  const float* wih = (const float*)d_in[7];
  const float* whh = (const float*)d_in[8];
  const float* bih = (const float*)d_in[9];
  const float* bhh = (const float*)d_in[10];
  const float* hw  = (const float*)d_in[11];
  const float* hdb = (const float*)d_in[12];
  const float* h0  = (const float*)d_in[13];
  const float* c0  = (const float*)d_in[14];
  float* out = (float*)d_out;

  if (ws_size < WS_NEED) return;
  char* ws = (char*)d_ws;
  unsigned short* feat16 = (unsigned short*)ws;
  unsigned short* spack  = (unsigned short*)(ws + FEAT16_B);

  hipFuncSetAttribute((const void*)lstm_kernel,
                      hipFuncAttributeMaxDynamicSharedMemorySize, SMEM_TOTAL);

  cnn_kernel<<<dim3(B_ * T_), dim3(256), 0, stream>>>(
      x, c1w, c1b, c2w, c2b, fcw, fcb, feat16);
  pack_kernel<<<dim3(137), dim3(256), 0, stream>>>(whh, wih, spack);
  lstm_kernel<<<dim3(8), dim3(256), SMEM_TOTAL, stream>>>(
      feat16, bih, bhh, h0, c0, hw, hdb, spack, out);
}

// Round 13
// 1750.943 us; speedup vs baseline: 1.4967x; 1.4967x over previous
//
#include <hip/hip_runtime.h>

#define B_ 128
#define T_ 270
#define XR 4104   // 8 + 64*64
#define H_ 256
#define HSTR 264                    // shorts per hls row (528 B)

#define LDSB_BYTES 151552           // 4 waves * 37 frags * 1 KB
#define HLS_OFF    151552
#define HEADP_OFF  160000
#define SMEM_TOTAL 160256           // <= 163840

// spack: full region 512 frags * 1 KB; compact kf8 region 64 * 512 B
#define SPACK_FULL_SHORTS  262144
#define SPACK_SHORTS       (262144 + 16384)

typedef __attribute__((ext_vector_type(8))) short short8v;
typedef __attribute__((ext_vector_type(4))) float f32x4;

__device__ inline unsigned short f2bf(float f) {
  unsigned u = __builtin_bit_cast(unsigned, f);
  u += 0x7fffu + ((u >> 16) & 1u);
  return (unsigned short)(u >> 16);
}
__device__ inline float sigm(float x) { return 1.0f / (1.0f + __expf(-x)); }
__device__ inline float tanh_f(float x) {
  float t = __expf(-2.0f * fabsf(x));
  float r = (1.0f - t) / (1.0f + t);
  return copysignf(r, x);
}
__device__ inline short8v pack8(const float* p) {
  float4 a = *(const float4*)p, b = *(const float4*)(p + 4);
  short8v v;
  v[0] = (short)f2bf(a.x); v[1] = (short)f2bf(a.y);
  v[2] = (short)f2bf(a.z); v[3] = (short)f2bf(a.w);
  v[4] = (short)f2bf(b.x); v[5] = (short)f2bf(b.y);
  v[6] = (short)f2bf(b.z); v[7] = (short)f2bf(b.w);
  return v;
}
__device__ inline short8v pinned(short8v v) {       // arch-VGPR pin
  union { short8v s; float f[4]; } u;
  u.s = v;
  asm volatile("" : "+v"(u.f[0]), "+v"(u.f[1]), "+v"(u.f[2]), "+v"(u.f[3]));
  return u.s;
}
__device__ inline short8v pinned_a(short8v v) {     // AGPR pin
  union { short8v s; float f[4]; } u;
  u.s = v;
  asm volatile("" : "+a"(u.f[0]), "+a"(u.f[1]), "+a"(u.f[2]), "+a"(u.f[3]));
  return u.s;
}
#define MFMA(a, b, c) __builtin_amdgcn_mfma_f32_16x16x32_bf16((a), (b), (c), 0, 0, 0)

// ws layout
#define FEAT16_B ((size_t)T_ * B_ * 16 * 2)        // 1,105,920
#define SPACK_B  ((size_t)SPACK_SHORTS * 2)        //   557,056
#define WS_NEED  (FEAT16_B + SPACK_B)

// ---------------------------------------------------------------------------
// Kernel 1: per-(b,t) CNN tower. One block per image. Writes bf16 feat.
// ---------------------------------------------------------------------------
__global__ __launch_bounds__(256) void cnn_kernel(
    const float* __restrict__ x,
    const float* __restrict__ c1w_, const float* __restrict__ c1b_,
    const float* __restrict__ c2w_, const float* __restrict__ c2b_,
    const float* __restrict__ fcw, const float* __restrict__ fcb,
    unsigned short* __restrict__ feat16)
{
  __shared__ float img[64 * 68];
  __shared__ float p1[2 * 15 * 16];
  __shared__ float p2[36];
  __shared__ float wsm[96];
  const int tid = threadIdx.x;
  const int bt = blockIdx.x;
  const int b = bt & 127, t = bt >> 7;

  const float* src = x + ((long)b * T_ + t) * XR;

  if (tid < 18) wsm[tid] = c1w_[tid];
  else if (tid < 20) wsm[tid] = c1b_[tid - 18];
  else if (tid < 92) wsm[tid] = c2w_[tid - 20];
  else if (tid < 96) wsm[tid] = c2b_[tid - 92];

  {
    const float4* s4 = (const float4*)(src + 8);
#pragma unroll
    for (int i0 = 0; i0 < 4; i0++) {
      int i = tid + i0 * 256;
      float4 v = s4[i];
      int e = i * 4;
      *((float4*)&img[(e >> 6) * 68 + (e & 63)]) = v;
    }
  }
  __syncthreads();

  if (tid < 225) {
    int py = tid / 15, px = tid - (tid / 15) * 15;
    float w0[9], w1[9];
#pragma unroll
    for (int j = 0; j < 9; j++) { w0[j] = wsm[j]; w1[j] = wsm[9 + j]; }
    const float b0 = wsm[18], b1v = wsm[19];
    float m0 = -1e30f, m1 = -1e30f;
    for (int dy = 0; dy < 4; dy++) {
      for (int dx = 0; dx < 4; dx++) {
        const float* ip = &img[(py * 4 + dy) * 68 + px * 4 + dx];
        float s0 = b0, s1 = b1v;
#pragma unroll
        for (int ky = 0; ky < 3; ky++) {
#pragma unroll
          for (int kx = 0; kx < 3; kx++) {
            float v = ip[ky * 68 + kx];
            s0 = fmaf(v, w0[ky * 3 + kx], s0);
            s1 = fmaf(v, w1[ky * 3 + kx], s1);
          }
        }
        m0 = fmaxf(m0, s0); m1 = fmaxf(m1, s1);
      }
    }
    p1[py * 16 + px] = fmaxf(m0, 0.f);
    p1[240 + py * 16 + px] = fmaxf(m1, 0.f);
  }
  __syncthreads();

  if (tid < 36) {
    int ch = tid / 9, rem = tid - ch * 9;
    int py = rem / 3, px = rem - py * 3;
    float m = -1e30f;
    for (int dy = 0; dy < 4; dy++) {
      for (int dx = 0; dx < 4; dx++) {
        int y = py * 4 + dy, xx = px * 4 + dx;
        float s = wsm[92 + ch];
#pragma unroll
        for (int ic = 0; ic < 2; ic++)
#pragma unroll
          for (int ky = 0; ky < 3; ky++)
#pragma unroll
            for (int kx = 0; kx < 3; kx++)
              s = fmaf(p1[ic * 240 + (y + ky) * 16 + xx + kx],
                       wsm[20 + ((ch * 2 + ic) * 3 + ky) * 3 + kx], s);
        m = fmaxf(m, s);
      }
    }
    p2[tid] = fmaxf(m, 0.f);
  }
  __syncthreads();

  unsigned short* fr = feat16 + ((long)t * B_ + b) * 16;
  if (tid < 8) {
    float s = fcb[tid];
#pragma unroll
    for (int j = 0; j < 36; j++) s = fmaf(p2[j], fcw[tid * 36 + j], s);
    fr[8 + tid] = f2bf(s);
  } else if (tid < 16) {
    fr[tid - 8] = f2bf(src[tid - 8]);
  }
}

// ---------------------------------------------------------------------------
// Kernel 1b: pack weights bf16 (same layout as round 12).
// Full: F=(w*16+u)*8+kf, addr F*512+lane*8; compact kf8: G=w*16+u, 256/G.
// ---------------------------------------------------------------------------
__global__ __launch_bounds__(256) void pack_kernel(
    const float* __restrict__ whh, const float* __restrict__ wih,
    unsigned short* __restrict__ spack)
{
  const int idx = blockIdx.x * 256 + threadIdx.x;
  if (idx < 32768) {
    const int lane = idx & 63, F = idx >> 6;
    const int kf = F & 7, u = (F >> 3) & 15, w = F >> 7;
    const int col = (u >> 2) * 256 + w * 64 + (u & 3) * 16 + (lane & 15);
    *(short8v*)(spack + (size_t)F * 512 + (size_t)lane * 8) =
        pack8(whh + col * 256 + kf * 32 + (lane >> 4) * 8);
  } else if (idx < 32768 + 2048) {
    const int i2 = idx - 32768;
    const int lane = i2 & 31, G = i2 >> 5;
    const int u = G & 15, w = G >> 4;
    const int col = (u >> 2) * 256 + w * 64 + (u & 3) * 16 + (lane & 15);
    *(short8v*)(spack + SPACK_FULL_SHORTS + (size_t)G * 256 + (size_t)lane * 8) =
        pack8(wih + col * 16 + (lane >> 4) * 8);
  }
}

// ---------------------------------------------------------------------------
// Kernel 2: LSTM, zero inter-block communication. 8 blocks x 16 rows, full
// 256 hidden dims per block. 256 thr = 4 waves (1/SIMD).
// ROUND-13 FIX: r12's in-loop stream loads had loop-INVARIANT addresses ->
// LLVM LICM hoisted all 43 frags out of the t-loop (~172 extra live regs) ->
// arch file 256 + spill -> 9.1 us/step. Fix: launder stream base pointers
// through asm volatile each iteration (address no longer provably invariant)
// + rebalanced tiers with headroom:
//   AGPR : acc(64) + kf0,kf1 (128)      = 192  (64 slack)
//   arch : kf2,kf3 pinned (128) + one 8-frag stream batch (32) + misc ~60
//   LDS  : kf4,kf5 (32) + kf6 u0..4 (5) = 37 frags, 148 KB
//   L2   : kf6 u5..15, kf7, kf8c = 43 frags/step, 6 batches, single-buffered
// ---------------------------------------------------------------------------
__global__ __launch_bounds__(256, 1) void lstm_kernel(
    const unsigned short* __restrict__ feat16,
    const float* __restrict__ bih, const float* __restrict__ bhh,
    const float* __restrict__ h0, const float* __restrict__ c0,
    const float* __restrict__ hw, const float* __restrict__ hdb,
    const unsigned short* __restrict__ spack, float* __restrict__ out)
{
  extern __shared__ char smem[];
  unsigned short* ldsB = (unsigned short*)smem;
  unsigned short* hls  = (unsigned short*)(smem + HLS_OFF);
  float* headp = (float*)(smem + HEADP_OFF);     // [4][16]

  const int tid = threadIdx.x;
  const int w = tid >> 6, lane = tid & 63;
  const int col15 = lane & 15, ko8 = (lane >> 4) * 8, rb = (lane >> 4) * 4;
  const int R0 = blockIdx.x * 16;
  const int ar = col15;                          // A-frag row

  const unsigned short* sb = spack + (size_t)(w * 16) * 8 * 512 + (size_t)lane * 8;
  const unsigned short* cb =
      spack + SPACK_FULL_SHORTS + (size_t)(w * 16) * 256 + (size_t)(lane & 31) * 8;
#define SFRAG(u, kf) (*(const short8v*)(sb + ((u) * 8 + (kf)) * 512))

  // ---- register tiers (init loads may be hoisted/CSE'd freely — intended)
  short8v bA0[16], bA1[16];            // AGPR: kf0, kf1
  short8v bV2[16], bV3[16];            // arch: kf2, kf3
#pragma unroll
  for (int u = 0; u < 16; u++) {
    bA0[u] = pinned_a(SFRAG(u, 0));
    bA1[u] = pinned_a(SFRAG(u, 1));
    bV2[u] = pinned(SFRAG(u, 2));
    bV3[u] = pinned(SFRAG(u, 3));
  }

  // ---- LDS tier: s<16: kf4,u=s ; s<32: kf5,u=s-16 ; s<37: kf6,u=s-32
#pragma unroll
  for (int s = 0; s < 37; s++) {
    const int u = (s < 16) ? s : (s < 32) ? (s - 16) : (s - 32);
    const int kf = (s < 16) ? 4 : (s < 32) ? 5 : 6;
    *(short8v*)&ldsB[((w * 37 + s) * 64 + lane) * 8] = SFRAG(u, kf);
  }
#define LB(s) (*(const short8v*)&ldsB[((w * 37 + (s)) * 64 + lane) * 8])

  // ---- per-lane constants
  float bsr[16], hwr[4];
#pragma unroll
  for (int u = 0; u < 16; u++) {
    const int col = (u >> 2) * 256 + w * 64 + (u & 3) * 16 + col15;
    bsr[u] = bih[col] + bhh[col];
  }
#pragma unroll
  for (int q = 0; q < 4; q++) hwr[q] = hw[w * 64 + q * 16 + col15];
  const float hdb0 = hdb[0];

  // ---- c-state in registers; h0 -> LDS
  float cs[4][4];
#pragma unroll
  for (int q = 0; q < 4; q++)
#pragma unroll
    for (int rr = 0; rr < 4; rr++) {
      const int row = rb + rr, d = w * 64 + q * 16 + col15;
      cs[q][rr] = c0[(R0 + row) * H_ + d];
      hls[row * HSTR + d] = f2bf(h0[(R0 + row) * H_ + d]);
    }
  __syncthreads();

#define HFRAG(kf) (*(const short8v*)&hls[ar * HSTR + (kf) * 32 + ko8])
  const short8v z8 = (short8v){0, 0, 0, 0, 0, 0, 0, 0};

  for (int t = 0; t < T_; t++) {
    // ---- LICM defeat: stream base pointers laundered per-iteration so the
    // 43 in-loop weight loads cannot be hoisted out of the t-loop (r12 bug).
    const unsigned short* sbt = sb;
    const unsigned short* cbt = cb;
    asm volatile("" : "+v"(sbt), "+v"(cbt));
#define SFT(u, kf) (*(const short8v*)(sbt + ((u) * 8 + (kf)) * 512))
#define CFT(u)     (*(const short8v*)(cbt + (u) * 256))

    // ---- head output for t-1
    if (w == 0 && lane < 16 && t > 0) {
      float s = hdb0 + headp[lane] + headp[16 + lane] + headp[32 + lane] + headp[48 + lane];
      out[(long)(R0 + lane) * T_ + (t - 1)] = s;
    }

    // feat A-frag (K slots 0..15 real, rest zero)
    short8v af8 = z8;
    if (ko8 < 16)
      af8 = *(const short8v*)(feat16 + ((size_t)t * B_ + R0 + ar) * 16 + ko8);

    f32x4 acc[16];
#pragma unroll
    for (int u = 0; u < 16; u++) acc[u] = (f32x4){0.f, 0.f, 0.f, 0.f};

    // ---- S1 issue: kf6 u5..12
    short8v s10 = SFT(5, 6),  s11 = SFT(6, 6),  s12 = SFT(7, 6),  s13 = SFT(8, 6);
    short8v s14 = SFT(9, 6),  s15 = SFT(10, 6), s16 = SFT(11, 6), s17 = SFT(12, 6);
    // AGPR tier: kf0, kf1 (covers S1 latency)
    {
      short8v a = HFRAG(0);
#pragma unroll
      for (int u = 0; u < 16; u++) acc[u] = MFMA(a, bA0[u], acc[u]);
    }
    {
      short8v a = HFRAG(1);
#pragma unroll
      for (int u = 0; u < 16; u++) acc[u] = MFMA(a, bA1[u], acc[u]);
    }
    // consume S1
    short8v a6 = HFRAG(6);
    acc[5]  = MFMA(a6, s10, acc[5]);   acc[6]  = MFMA(a6, s11, acc[6]);
    acc[7]  = MFMA(a6, s12, acc[7]);   acc[8]  = MFMA(a6, s13, acc[8]);
    acc[9]  = MFMA(a6, s14, acc[9]);   acc[10] = MFMA(a6, s15, acc[10]);
    acc[11] = MFMA(a6, s16, acc[11]);  acc[12] = MFMA(a6, s17, acc[12]);

    // ---- S2 issue: kf6 u13..15 + kf7 u0..4
    short8v s20 = SFT(13, 6), s21 = SFT(14, 6), s22 = SFT(15, 6);
    short8v s23 = SFT(0, 7),  s24 = SFT(1, 7),  s25 = SFT(2, 7),  s26 = SFT(3, 7), s27 = SFT(4, 7);
    // arch tier: kf2, kf3
    {
      short8v a = HFRAG(2);
#pragma unroll
      for (int u = 0; u < 16; u++) acc[u] = MFMA(a, bV2[u], acc[u]);
    }
    {
      short8v a = HFRAG(3);
#pragma unroll
      for (int u = 0; u < 16; u++) acc[u] = MFMA(a, bV3[u], acc[u]);
    }
    // consume S2
    short8v a7 = HFRAG(7);
    acc[13] = MFMA(a6, s20, acc[13]);  acc[14] = MFMA(a6, s21, acc[14]);
    acc[15] = MFMA(a6, s22, acc[15]);
    acc[0]  = MFMA(a7, s23, acc[0]);   acc[1]  = MFMA(a7, s24, acc[1]);
    acc[2]  = MFMA(a7, s25, acc[2]);   acc[3]  = MFMA(a7, s26, acc[3]);
    acc[4]  = MFMA(a7, s27, acc[4]);

    // ---- S3 issue: kf7 u5..12
    short8v s30 = SFT(5, 7),  s31 = SFT(6, 7),  s32 = SFT(7, 7),  s33 = SFT(8, 7);
    short8v s34 = SFT(9, 7),  s35 = SFT(10, 7), s36 = SFT(11, 7), s37 = SFT(12, 7);
    // LDS tier: kf4
    {
      short8v a = HFRAG(4);
#pragma unroll
      for (int u = 0; u < 16; u++) acc[u] = MFMA(a, LB(u), acc[u]);
    }
    // consume S3
    acc[5]  = MFMA(a7, s30, acc[5]);   acc[6]  = MFMA(a7, s31, acc[6]);
    acc[7]  = MFMA(a7, s32, acc[7]);   acc[8]  = MFMA(a7, s33, acc[8]);
    acc[9]  = MFMA(a7, s34, acc[9]);   acc[10] = MFMA(a7, s35, acc[10]);
    acc[11] = MFMA(a7, s36, acc[11]);  acc[12] = MFMA(a7, s37, acc[12]);

    // ---- S4 issue: kf7 u13..15 + kf8 u0..4 (compact)
    short8v s40 = SFT(13, 7), s41 = SFT(14, 7), s42 = SFT(15, 7);
    short8v c40 = CFT(0), c41 = CFT(1), c42 = CFT(2), c43 = CFT(3), c44 = CFT(4);
    // LDS tier: kf5
    {
      short8v a = HFRAG(5);
#pragma unroll
      for (int u = 0; u < 16; u++) acc[u] = MFMA(a, LB(16 + u), acc[u]);
    }
    // consume S4
    c40 = (lane < 32) ? c40 : z8;  c41 = (lane < 32) ? c41 : z8;
    c42 = (lane < 32) ? c42 : z8;  c43 = (lane < 32) ? c43 : z8;
    c44 = (lane < 32) ? c44 : z8;
    acc[13] = MFMA(a7, s40, acc[13]);  acc[14] = MFMA(a7, s41, acc[14]);
    acc[15] = MFMA(a7, s42, acc[15]);
    acc[0]  = MFMA(af8, c40, acc[0]);  acc[1]  = MFMA(af8, c41, acc[1]);
    acc[2]  = MFMA(af8, c42, acc[2]);  acc[3]  = MFMA(af8, c43, acc[3]);
    acc[4]  = MFMA(af8, c44, acc[4]);

    // ---- S5 issue: kf8 u5..12 (compact)
    short8v c50 = CFT(5),  c51 = CFT(6),  c52 = CFT(7),  c53 = CFT(8);
    short8v c54 = CFT(9),  c55 = CFT(10), c56 = CFT(11), c57 = CFT(12);
    // LDS tier: kf6 u0..4
    acc[0] = MFMA(a6, LB(32), acc[0]);
    acc[1] = MFMA(a6, LB(33), acc[1]);
    acc[2] = MFMA(a6, LB(34), acc[2]);
    acc[3] = MFMA(a6, LB(35), acc[3]);
    acc[4] = MFMA(a6, LB(36), acc[4]);
    // consume S5
    c50 = (lane < 32) ? c50 : z8;  c51 = (lane < 32) ? c51 : z8;
    c52 = (lane < 32) ? c52 : z8;  c53 = (lane < 32) ? c53 : z8;
    c54 = (lane < 32) ? c54 : z8;  c55 = (lane < 32) ? c55 : z8;
    c56 = (lane < 32) ? c56 : z8;  c57 = (lane < 32) ? c57 : z8;
    acc[5]  = MFMA(af8, c50, acc[5]);   acc[6]  = MFMA(af8, c51, acc[6]);
    acc[7]  = MFMA(af8, c52, acc[7]);   acc[8]  = MFMA(af8, c53, acc[8]);
    acc[9]  = MFMA(af8, c54, acc[9]);   acc[10] = MFMA(af8, c55, acc[10]);
    acc[11] = MFMA(af8, c56, acc[11]);  acc[12] = MFMA(af8, c57, acc[12]);

    // ---- S6: kf8 u13..15
    short8v c60 = CFT(13), c61 = CFT(14), c62 = CFT(15);
    c60 = (lane < 32) ? c60 : z8;  c61 = (lane < 32) ? c61 : z8;
    c62 = (lane < 32) ? c62 : z8;
    acc[13] = MFMA(af8, c60, acc[13]);
    acc[14] = MFMA(af8, c61, acc[14]);
    acc[15] = MFMA(af8, c62, acc[15]);

    __syncthreads();   // all h(t) reads + headp(t-1) reads complete

    // ---- in-register LSTM cell: 16 cells/lane + h publish + head partial
    float ps[4] = {0.f, 0.f, 0.f, 0.f};
#pragma unroll
    for (int q = 0; q < 4; q++)
#pragma unroll
      for (int rr = 0; rr < 4; rr++) {
        float i_ = acc[q][rr]      + bsr[q];
        float f_ = acc[4 + q][rr]  + bsr[4 + q];
        float g_ = acc[8 + q][rr]  + bsr[8 + q];
        float o_ = acc[12 + q][rr] + bsr[12 + q];
        float cn = sigm(f_) * cs[q][rr] + sigm(i_) * tanh_f(g_);
        cs[q][rr] = cn;
        float hn = sigm(o_) * tanh_f(cn);
        hls[(rb + rr) * HSTR + w * 64 + q * 16 + col15] = f2bf(hn);
        ps[rr] += hn * hwr[q];
      }
#pragma unroll
    for (int off = 1; off <= 8; off <<= 1)
#pragma unroll
      for (int rr = 0; rr < 4; rr++) ps[rr] += __shfl_xor(ps[rr], off);
    if (col15 == 0)
#pragma unroll
      for (int rr = 0; rr < 4; rr++) headp[w * 16 + rb + rr] = ps[rr];

    __syncthreads();   // h(t+1) + headp(t) visible block-wide
  }

  // ---- final head output (t = T-1)
  if (w == 0 && lane < 16) {
    float s = hdb0 + headp[lane] + headp[16 + lane] + headp[32 + lane] + headp[48 + lane];
    out[(long)(R0 + lane) * T_ + (T_ - 1)] = s;
  }
}

// ---------------------------------------------------------------------------
extern "C" void kernel_launch(void* const* d_in, const int* in_sizes, int n_in,
                              void* d_out, int out_size, void* d_ws, size_t ws_size,
                              hipStream_t stream) {
  const float* x   = (const float*)d_in[0];
  const float* c1w = (const float*)d_in[1];
  const float* c1b = (const float*)d_in[2];
  const float* c2w = (const float*)d_in[3];
  const float* c2b = (const float*)d_in[4];
  const float* fcw = (const float*)d_in[5];
  const float* fcb = (const float*)d_in[6];
  const float* wih = (const float*)d_in[7];
  const float* whh = (const float*)d_in[8];
  const float* bih = (const float*)d_in[9];
  const float* bhh = (const float*)d_in[10];
  const float* hw  = (const float*)d_in[11];
  const float* hdb = (const float*)d_in[12];
  const float* h0  = (const float*)d_in[13];
  const float* c0  = (const float*)d_in[14];
  float* out = (float*)d_out;

  if (ws_size < WS_NEED) return;
  char* ws = (char*)d_ws;
  unsigned short* feat16 = (unsigned short*)ws;
  unsigned short* spack  = (unsigned short*)(ws + FEAT16_B);

  hipFuncSetAttribute((const void*)lstm_kernel,
                      hipFuncAttributeMaxDynamicSharedMemorySize, SMEM_TOTAL);

  cnn_kernel<<<dim3(B_ * T_), dim3(256), 0, stream>>>(
      x, c1w, c1b, c2w, c2b, fcw, fcb, feat16);
  pack_kernel<<<dim3(137), dim3(256), 0, stream>>>(whh, wih, spack);
  lstm_kernel<<<dim3(8), dim3(256), SMEM_TOTAL, stream>>>(
      feat16, bih, bhh, h0, c0, hw, hdb, spack, out);
}